// Round 7
// baseline (243.372 us; speedup 1.0000x reference)
//
#include <hip/hip_runtime.h>
#include <hip/hip_bf16.h>
#include <math.h>

#define NPTS 100000
#define NPAD 100352      // 784*128; 98 row-tiles per XCD
#define KCOMP 64

typedef float v4f __attribute__((ext_vector_type(4)));
typedef __bf16 v8bf __attribute__((ext_vector_type(8)));
typedef __bf16 v4bf __attribute__((ext_vector_type(4)));

// Fragment-native operand layouts (no LDS anywhere in the GEMM):
//   Xb[rt][ks(8)][m(8)][lane(64)][e(8)]  : X[rt*128 + m*16 + (l&15)][ks*32 + (l>>4)*8 + e]
//   Bt[cw(16)][ks(8)][n(4)][lane(64)][e(8)]: B[cw*64 + n*16 + (l&15)][ks*32 + (l>>4)*8 + e]
// -> every MFMA fragment load = one coalesced global_load_dwordx4 (base + lane*16).

// ---------- kernel 1: per-component prep (Cholesky of I+M^T M, B = L^-1 M^T) ----------
__global__ __launch_bounds__(256) void prep_comp(const float* __restrict__ M,
                                                 const float* __restrict__ pi,
                                                 __bf16* __restrict__ Bt,
                                                 float* __restrict__ cvec,
                                                 float logSA) {
    __shared__ float Ml[256][16];
    __shared__ float S[16][17];
    __shared__ float sh_logpi;
    const int k = blockIdx.x, t = threadIdx.x;

    const float4* src = (const float4*)(M + (size_t)k * 4096 + (size_t)t * 16);
    float4 a0 = src[0], a1 = src[1], a2 = src[2], a3 = src[3];
    ((float4*)Ml[t])[0] = a0; ((float4*)Ml[t])[1] = a1;
    ((float4*)Ml[t])[2] = a2; ((float4*)Ml[t])[3] = a3;

    if (t < 64) {
        float v = pi[t];
        float mx = v;
        for (int off = 32; off; off >>= 1) mx = fmaxf(mx, __shfl_xor(mx, off));
        float e = __expf(v - mx);
        float s = e;
        for (int off = 32; off; off >>= 1) s += __shfl_xor(s, off);
        if (t == 0) sh_logpi = pi[k] - mx - logf(s);
    }
    __syncthreads();

    {
        int r = t >> 4, c = t & 15;
        float s = (r == c) ? 1.0f : 0.0f;
        for (int p = 0; p < 256; ++p) s += Ml[p][r] * Ml[p][c];
        S[r][c] = s;
    }
    __syncthreads();

    for (int j = 0; j < 16; ++j) {
        if (t == 0) S[j][j] = sqrtf(S[j][j]);
        __syncthreads();
        if (t > j && t < 16) S[t][j] = S[t][j] / S[j][j];
        __syncthreads();
        {
            int r = t >> 4, c = t & 15;
            if (r > j && c > j && c <= r) S[r][c] -= S[r][j] * S[c][j];
        }
        __syncthreads();
    }

    if (t == 0) {
        float ldet = 0.0f;
        for (int j = 0; j < 16; ++j) ldet += logf(S[j][j]);
        cvec[k] = logSA - ldet + sh_logpi;
    }

    float m[16] = {a0.x, a0.y, a0.z, a0.w, a1.x, a1.y, a1.z, a1.w,
                   a2.x, a2.y, a2.z, a2.w, a3.x, a3.y, a3.z, a3.w};
    float y[16];
#pragma unroll
    for (int r = 0; r < 16; ++r) {
        float v = m[r];
#pragma unroll
        for (int q = 0; q < r; ++q) v -= S[r][q] * y[q];
        y[r] = v / S[r][r];
    }
    // write fragment-native: cw = k>>2, n = k&3, l = ((t>>3)&3)*16 + r, ks = t>>5, e = t&7
    const int cw = k >> 2, n = k & 3;
    const int ks = t >> 5, e = t & 7;
    const int lbase = ((t >> 3) & 3) * 16;
#pragma unroll
    for (int r = 0; r < 16; ++r) {
        const size_t off = (size_t)cw * 16384 + (size_t)ks * 2048 + (size_t)n * 512
                         + (size_t)(lbase + r) * 8 + e;
        Bt[off] = (__bf16)y[r];
    }
}

// ---------- kernel 2: X fp32 -> bf16 into fragment-native layout ----------
// block = (rt, half): 64 rows x 256 cols; LDS transpose staging.
__global__ __launch_bounds__(256) void convert_X(const float* __restrict__ X,
                                                 __bf16* __restrict__ Xb) {
    __shared__ __bf16 T[64][264];
    const int b = blockIdx.x;
    const int rt = b >> 1, half = b & 1;
    const int n0 = rt * 128 + half * 64;
    const int t = threadIdx.x;

    // phase 1: coalesced f32 reads -> bf16 -> LDS (row uniform per wave, 8B/lane)
#pragma unroll
    for (int j = 0; j < 16; ++j) {
        const int u = j * 256 + t;
        const int r = u >> 6, c4 = u & 63;
        const int n = n0 + r;
        float4 v = make_float4(0.f, 0.f, 0.f, 0.f);
        if (n < NPTS) v = ((const float4*)X)[(size_t)n * 64 + c4];
        v4bf o = {(__bf16)v.x, (__bf16)v.y, (__bf16)v.z, (__bf16)v.w};
        *(v4bf*)&T[r][c4 * 4] = o;
    }
    __syncthreads();

    // phase 2: fragment-native coalesced writes (16B/lane, lane-consecutive)
#pragma unroll
    for (int j = 0; j < 8; ++j) {
        const int ks = j;
        const int mh = (t >> 6) & 3;         // wave index
        const int l = t & 63;
        const int row = mh * 16 + (l & 15);
        const int col = ks * 32 + (l >> 4) * 8;
        v8bf val = *(const v8bf*)&T[row][col];
        const size_t off = (size_t)rt * 32768 + (size_t)ks * 4096
                         + (size_t)(half * 4 + mh) * 512 + (size_t)l * 8;
        *(v8bf*)(Xb + off) = val;
    }
}

// ---------- kernel 3: LDS-free streaming GEMM + fused density epilogue ----------
// Each WAVE owns 128x64 output jobs; fragments loaded straight from L2;
// zero barriers, zero LDS. acc = mfma(bg, af) so the r-reduction is lane-local.
__global__ __launch_bounds__(256, 2) void gemm_density(const __bf16* __restrict__ Xb,
                                                       const __bf16* __restrict__ Bt,
                                                       const float* __restrict__ cvec,
                                                       float* __restrict__ dens) {
    const int bid = blockIdx.x;
    const int xcd = bid & 7, ib = bid >> 3;          // 512 blocks: 64 per XCD
    const int w = threadIdx.x >> 6, lane = threadIdx.x & 63;
    const int q = ib * 4 + w;                        // wave id within XCD: 0..255
    const int njobs = (q < 32) ? 7 : 6;              // 1568 jobs/XCD = 32*7 + 224*6
    const int laneoff = lane * 8;

    for (int j = 0; j < njobs; ++j) {
        const int flat = j * 256 + q;                // consecutive waves -> clustered rt
        const int rt = xcd * 98 + (flat >> 4);
        const int cw = flat & 15;
        const __bf16* Ab = Xb + ((size_t)rt << 15) + laneoff;
        const __bf16* Bb = Bt + ((size_t)cw << 14) + laneoff;

        v4f acc[8][4] = {};
        v8bf a[2][8], b[2][4];
#pragma unroll
        for (int m = 0; m < 8; ++m) a[0][m] = *(const v8bf*)(Ab + m * 512);
#pragma unroll
        for (int n = 0; n < 4; ++n) b[0][n] = *(const v8bf*)(Bb + n * 512);

#pragma unroll
        for (int ks = 0; ks < 8; ++ks) {
            const int cur = ks & 1;
            if (ks < 7) {
                const __bf16* An = Ab + (ks + 1) * 4096;
                const __bf16* Bn = Bb + (ks + 1) * 2048;
#pragma unroll
                for (int m = 0; m < 8; ++m) a[cur ^ 1][m] = *(const v8bf*)(An + m * 512);
#pragma unroll
                for (int n = 0; n < 4; ++n) b[cur ^ 1][n] = *(const v8bf*)(Bn + n * 512);
            }
#pragma unroll
            for (int m = 0; m < 8; ++m)
#pragma unroll
                for (int n = 0; n < 4; ++n)
                    acc[m][n] = __builtin_amdgcn_mfma_f32_16x16x32_bf16(b[cur][n], a[cur][m], acc[m][n], 0, 0, 0);
        }

        // epilogue: per-lane square-sum over 4 regs (r-dim), + xor16/xor32 over hi groups
#pragma unroll
        for (int m = 0; m < 8; ++m) {
#pragma unroll
            for (int n = 0; n < 4; ++n) {
                v4f qv = acc[m][n];
                float s = qv[0] * qv[0] + qv[1] * qv[1] + qv[2] * qv[2] + qv[3] * qv[3];
                s += __shfl_xor(s, 16);
                s += __shfl_xor(s, 32);
                if (lane < 16) {
                    const int kc = cw * 4 + n;
                    const float d = cvec[kc] - 128.0f * __logf(1.0f - s);
                    dens[(size_t)kc * NPAD + (size_t)rt * 128 + m * 16 + lane] = d;
                }
            }
        }
    }
}

// ---------- kernel 4: logsumexp over k, global sum ----------
__global__ __launch_bounds__(256) void reduce_ll(const float* __restrict__ dens,
                                                 float* __restrict__ out) {
    const int n = blockIdx.x * 256 + threadIdx.x;
    float local = 0.0f;
    if (n < NPTS) {
        float m = dens[n];
        float s = 1.0f;
        for (int k = 1; k < 64; ++k) {
            float d = dens[(size_t)k * NPAD + n];
            float mn = fmaxf(m, d);
            s = s * __expf(m - mn) + __expf(d - mn);
            m = mn;
        }
        local = m + __logf(s);
    }
    for (int off = 32; off; off >>= 1) local += __shfl_down(local, off);
    __shared__ float part[4];
    const int wv = threadIdx.x >> 6, lane = threadIdx.x & 63;
    if (lane == 0) part[wv] = local;
    __syncthreads();
    if (threadIdx.x == 0) atomicAdd(out, part[0] + part[1] + part[2] + part[3]);
}

extern "C" void kernel_launch(void* const* d_in, const int* in_sizes, int n_in,
                              void* d_out, int out_size, void* d_ws, size_t ws_size,
                              hipStream_t stream) {
    const float* X  = (const float*)d_in[0];
    const float* M  = (const float*)d_in[1];
    const float* pi = (const float*)d_in[2];
    float* out = (float*)d_out;

    char* ws = (char*)d_ws;
    __bf16* Xb    = (__bf16*)ws;                          // 784*32768*2   = 51,380,224
    __bf16* Bt    = (__bf16*)(ws + 51380224);             // 16*16384*2    =    524,288
    float*  dens  = (float*)(ws + 51904512);              // 64*100352*4   = 25,690,112
    float*  cvec  = (float*)(ws + 77594624);              // 256 B

    const double half_p = 128.0;
    const float logSA = (float)(lgamma(half_p) - log(2.0) - half_p * log(M_PI));

    hipMemsetAsync(d_out, 0, sizeof(float), stream);
    prep_comp<<<64, 256, 0, stream>>>(M, pi, Bt, cvec, logSA);
    convert_X<<<1568, 256, 0, stream>>>(X, Xb);           // 784 tiles x 2 halves
    gemm_density<<<512, 256, 0, stream>>>(Xb, Bt, cvec, dens);   // 2048 waves, persistent
    reduce_ll<<<391, 256, 0, stream>>>(dens, out);
}

// Round 8
// 171.717 us; speedup vs baseline: 1.4173x; 1.4173x over previous
//
#include <hip/hip_runtime.h>
#include <hip/hip_bf16.h>
#include <math.h>

#define NPTS 100000
#define NPAD 100352      // 784*128; 98 row-tiles per XCD
#define KCOMP 64

typedef float v4f __attribute__((ext_vector_type(4)));
typedef __bf16 v8bf __attribute__((ext_vector_type(8)));
typedef __bf16 v4bf __attribute__((ext_vector_type(4)));

// Tiled operand layout: [tile][kt(8)][g(4)][r(128)][8 elems]
//   flat granule f = g*128 + r;  offset = (tile*8 + kt)*4096 + f*8  (elems)
// -> global_load_lds per-lane f = base+lane is contiguous 1KB/instr; LDS order is
//    granule-column-major so fragment reads are 256B runs per 16-lane group => 0 conflicts.

__device__ __forceinline__ void gload_lds16(const void* g, void* lds) {
    __builtin_amdgcn_global_load_lds(
        (const __attribute__((address_space(1))) void*)(uintptr_t)g,
        (__attribute__((address_space(3))) void*)(uint32_t)(uintptr_t)lds,
        16, 0, 0);
}

// ---------- kernel 1: per-component prep (Cholesky of I+M^T M, B = L^-1 M^T) ----------
__global__ __launch_bounds__(256) void prep_comp(const float* __restrict__ M,
                                                 const float* __restrict__ pi,
                                                 __bf16* __restrict__ Bt,
                                                 float* __restrict__ cvec,
                                                 float logSA) {
    __shared__ float Ml[256][16];
    __shared__ float S[16][17];
    __shared__ float sh_logpi;
    const int k = blockIdx.x, t = threadIdx.x;

    const float4* src = (const float4*)(M + (size_t)k * 4096 + (size_t)t * 16);
    float4 a0 = src[0], a1 = src[1], a2 = src[2], a3 = src[3];
    ((float4*)Ml[t])[0] = a0; ((float4*)Ml[t])[1] = a1;
    ((float4*)Ml[t])[2] = a2; ((float4*)Ml[t])[3] = a3;

    if (t < 64) {
        float v = pi[t];
        float mx = v;
        for (int off = 32; off; off >>= 1) mx = fmaxf(mx, __shfl_xor(mx, off));
        float e = __expf(v - mx);
        float s = e;
        for (int off = 32; off; off >>= 1) s += __shfl_xor(s, off);
        if (t == 0) sh_logpi = pi[k] - mx - logf(s);
    }
    __syncthreads();

    {
        int r = t >> 4, c = t & 15;
        float s = (r == c) ? 1.0f : 0.0f;
        for (int p = 0; p < 256; ++p) s += Ml[p][r] * Ml[p][c];
        S[r][c] = s;
    }
    __syncthreads();

    for (int j = 0; j < 16; ++j) {
        if (t == 0) S[j][j] = sqrtf(S[j][j]);
        __syncthreads();
        if (t > j && t < 16) S[t][j] = S[t][j] / S[j][j];
        __syncthreads();
        {
            int r = t >> 4, c = t & 15;
            if (r > j && c > j && c <= r) S[r][c] -= S[r][j] * S[c][j];
        }
        __syncthreads();
    }

    if (t == 0) {
        float ldet = 0.0f;
        for (int j = 0; j < 16; ++j) ldet += logf(S[j][j]);
        cvec[k] = logSA - ldet + sh_logpi;
    }

    float m[16] = {a0.x, a0.y, a0.z, a0.w, a1.x, a1.y, a1.z, a1.w,
                   a2.x, a2.y, a2.z, a2.w, a3.x, a3.y, a3.z, a3.w};
    float y[16];
#pragma unroll
    for (int r = 0; r < 16; ++r) {
        float v = m[r];
#pragma unroll
        for (int q = 0; q < r; ++q) v -= S[r][q] * y[q];
        y[r] = v / S[r][r];
    }
    // write tiled: crow = k*16+r (the GEMM "col"), p = t (K dim)
#pragma unroll
    for (int r = 0; r < 16; ++r) {
        const int crow = k * 16 + r;
        const size_t off = (size_t)((crow >> 7) * 32 + (t >> 3)) * 1024
                         + (size_t)(crow & 127) * 8 + (t & 7);
        Bt[off] = (__bf16)y[r];
    }
}

// ---------- kernel 2: X fp32 -> bf16, transposed into tiled layout ----------
__global__ __launch_bounds__(256) void convert_X(const float* __restrict__ X,
                                                 __bf16* __restrict__ Xb) {
    __shared__ __bf16 T[64][264];
    const int b = blockIdx.x;
    const int rt = b >> 1, half = b & 1;
    const int n0 = rt * 128 + half * 64;
    const int t = threadIdx.x;

#pragma unroll
    for (int j = 0; j < 16; ++j) {
        const int u = j * 256 + t;
        const int r = u >> 6, c4 = u & 63;
        const int n = n0 + r;
        float4 v = make_float4(0.f, 0.f, 0.f, 0.f);
        if (n < NPTS) v = ((const float4*)X)[(size_t)n * 64 + c4];
        v4bf o = {(__bf16)v.x, (__bf16)v.y, (__bf16)v.z, (__bf16)v.w};
        *(v4bf*)&T[r][c4 * 4] = o;
    }
    __syncthreads();

#pragma unroll
    for (int j = 0; j < 8; ++j) {
        const int fo = j * 256 + t;
        const int gk = fo >> 6, r = fo & 63;
        v8bf val = *(const v8bf*)&T[r][gk * 8];
        *(v8bf*)(Xb + (size_t)(rt * 32 + gk) * 1024 + (size_t)(half * 64 + r) * 8) = val;
    }
}

// ---------- kernel 3: persistent GEMM, 3-deep ring + counted vmcnt(4) + raw barrier ----------
__global__ __launch_bounds__(256, 3) void gemm_density(const __bf16* __restrict__ Xb,
                                                       const __bf16* __restrict__ Bt,
                                                       const float* __restrict__ cvec,
                                                       float* __restrict__ dens) {
    __shared__ __bf16 As[3][4096];   // 8 KB per buf, 3-deep ring: 48 KB total w/ Bs
    __shared__ __bf16 Bs[3][4096];
    const int bid = blockIdx.x;
    const int x = bid & 7;           // XCD
    const int i = bid >> 3;          // 0..95 within XCD
    const int xbase = x * 98;
    const int tid = threadIdx.x;
    const int w = tid >> 6, lane = tid & 63;
    const int wm = w >> 1, wn = w & 1;
    const int lo = lane & 15, hi = lane >> 4;

    const int njobs = (i < 16) ? 9 : 8;      // 784 jobs/XCD over 96 blocks
    const int nslots = njobs << 3;

#define SLOT_RC(s, rt_, ct_) do {                          \
    const int jx_ = (s) >> 3;                              \
    const int Jl_ = i + jx_ * 96;                          \
    rt_ = xbase + (Jl_ >> 3); ct_ = Jl_ & 7;               \
} while (0)

#define STAGE(buf, s) do {                                                       \
    int rt_, ct_;  SLOT_RC(s, rt_, ct_);                                         \
    const int kt_ = (s) & 7;                                                     \
    _Pragma("unroll")                                                            \
    for (int q = 0; q < 2; ++q) {                                                \
        const int fb = (q << 8) + (w << 6);   /* wave-uniform granule base */    \
        const int f = fb + lane;                                                 \
        gload_lds16(Xb + ((size_t)(rt_ * 8 + kt_) * 512 + f) * 8,                \
                    As[buf] + ((size_t)fb << 3));                                \
        gload_lds16(Bt + ((size_t)(ct_ * 8 + kt_) * 512 + f) * 8,                \
                    Bs[buf] + ((size_t)fb << 3));                                \
    }                                                                            \
} while (0)

    // prologue: stage slots 0 and 1 (8 loads/thread in flight)
    STAGE(0, 0);
    STAGE(1, 1);

    v4f acc[4][4] = {};
    int buf = 0, sb = 2;                     // compute buffer, stage buffer (s+2)%3
    for (int s = 0; s < nslots; ++s) {
        // wait for slot-s loads only (4 newer stay in flight); raw barrier (no drain)
        if (s < nslots - 1) {
            asm volatile("s_waitcnt vmcnt(4)" ::: "memory");
        } else {
            asm volatile("s_waitcnt vmcnt(0)" ::: "memory");
        }
        __builtin_amdgcn_s_barrier();
        asm volatile("" ::: "memory");

        // stage slot s+2 into buf (s+2)%3 == (s-1)%3 (its readers finished pre-barrier)
        if (s + 2 < nslots) STAGE(sb, s + 2);

        // fragment reads: contiguous 256B per 16-lane group -> conflict-free
        v8bf af[4], bg[4];
#pragma unroll
        for (int m = 0; m < 4; ++m)
            af[m] = *(const v8bf*)&As[buf][((hi << 7) + wm * 64 + m * 16 + lo) << 3];
#pragma unroll
        for (int n = 0; n < 4; ++n)
            bg[n] = *(const v8bf*)&Bs[buf][((hi << 7) + wn * 64 + n * 16 + lo) << 3];
#pragma unroll
        for (int m = 0; m < 4; ++m)
#pragma unroll
            for (int n = 0; n < 4; ++n)
                acc[m][n] = __builtin_amdgcn_mfma_f32_16x16x32_bf16(af[m], bg[n], acc[m][n], 0, 0, 0);

        if ((s & 7) == 7) {
            int rt, ct;
            SLOT_RC(s, rt, ct);
            const int row0 = rt << 7, col0 = ct << 7;
#pragma unroll
            for (int m = 0; m < 4; ++m) {
                const int rowb = row0 + wm * 64 + m * 16 + hi * 4;
#pragma unroll
                for (int n = 0; n < 4; ++n) {
                    const int kc = (col0 >> 4) + (wn << 2) + n;
                    v4f q = acc[m][n] * acc[m][n];
#pragma unroll
                    for (int off = 1; off < 16; off <<= 1) {
                        v4f tq;
                        tq[0] = __shfl_xor(q[0], off);
                        tq[1] = __shfl_xor(q[1], off);
                        tq[2] = __shfl_xor(q[2], off);
                        tq[3] = __shfl_xor(q[3], off);
                        q += tq;
                    }
                    if (lo < 4) {
                        const float d = cvec[kc] - 128.0f * __logf(1.0f - q[lo]);
                        dens[(size_t)kc * NPAD + rowb + lo] = d;
                    }
                    acc[m][n] = (v4f)(0.0f);
                }
            }
        }

        buf = (buf == 2) ? 0 : buf + 1;
        sb  = (sb == 2) ? 0 : sb + 1;
    }
#undef STAGE
#undef SLOT_RC
}

// ---------- kernel 4: logsumexp over k, global sum ----------
__global__ __launch_bounds__(256) void reduce_ll(const float* __restrict__ dens,
                                                 float* __restrict__ out) {
    const int n = blockIdx.x * 256 + threadIdx.x;
    float local = 0.0f;
    if (n < NPTS) {
        float m = dens[n];
        float s = 1.0f;
        for (int k = 1; k < 64; ++k) {
            float d = dens[(size_t)k * NPAD + n];
            float mn = fmaxf(m, d);
            s = s * __expf(m - mn) + __expf(d - mn);
            m = mn;
        }
        local = m + __logf(s);
    }
    for (int off = 32; off; off >>= 1) local += __shfl_down(local, off);
    __shared__ float part[4];
    const int wv = threadIdx.x >> 6, lane = threadIdx.x & 63;
    if (lane == 0) part[wv] = local;
    __syncthreads();
    if (threadIdx.x == 0) atomicAdd(out, part[0] + part[1] + part[2] + part[3]);
}

extern "C" void kernel_launch(void* const* d_in, const int* in_sizes, int n_in,
                              void* d_out, int out_size, void* d_ws, size_t ws_size,
                              hipStream_t stream) {
    const float* X  = (const float*)d_in[0];
    const float* M  = (const float*)d_in[1];
    const float* pi = (const float*)d_in[2];
    float* out = (float*)d_out;

    char* ws = (char*)d_ws;
    __bf16* Xb    = (__bf16*)ws;                          // 784*32768*2   = 51,380,224
    __bf16* Bt    = (__bf16*)(ws + 51380224);             // 16*16384*2... =    524,288
    float*  dens  = (float*)(ws + 51904512);              // 64*100352*4   = 25,690,112
    float*  cvec  = (float*)(ws + 77594624);              // 256 B

    const double half_p = 128.0;
    const float logSA = (float)(lgamma(half_p) - log(2.0) - half_p * log(M_PI));

    hipMemsetAsync(d_out, 0, sizeof(float), stream);
    prep_comp<<<64, 256, 0, stream>>>(M, pi, Bt, cvec, logSA);
    convert_X<<<1568, 256, 0, stream>>>(X, Xb);           // 784 tiles x 2 halves
    gemm_density<<<768, 256, 0, stream>>>(Xb, Bt, cvec, dens);   // persistent, 3/CU
    reduce_ll<<<391, 256, 0, stream>>>(dens, out);
}

// Round 9
// 134.254 us; speedup vs baseline: 1.8128x; 1.2790x over previous
//
#include <hip/hip_runtime.h>
#include <hip/hip_bf16.h>
#include <math.h>

#define NPTS 100000
#define NSTRIPE 1568     // 64-row stripes; 196 per XCD
#define KCOMP 64

typedef float v4f __attribute__((ext_vector_type(4)));
typedef __bf16 v8bf __attribute__((ext_vector_type(8)));
typedef __bf16 v4bf __attribute__((ext_vector_type(4)));

// Fragment-native layouts (NO LDS, NO barriers in the GEMM):
//   Xb[st(1568)][ks(8)][m(4)][lane(64)][e(8)] : X[st*64 + m*16 + (l&15)][ks*32 + (l>>4)*8 + e]
//   Bt[cw(16)][ks(8)][n(4)][lane(64)][e(8)]   : B[cw*64 + n*16 + (l&15)][ks*32 + (l>>4)*8 + e]
// Every fragment load = one coalesced global_load_dwordx4 (base + lane*16).
// dens_t[point][64 comps] f32 -- written as float4 per lane, read contiguously.

// ---------- kernel 1: per-component prep (Cholesky of I+M^T M, B = L^-1 M^T) ----------
__global__ __launch_bounds__(256) void prep_comp(const float* __restrict__ M,
                                                 const float* __restrict__ pi,
                                                 __bf16* __restrict__ Bt,
                                                 float* __restrict__ cvec,
                                                 float logSA) {
    __shared__ float Ml[256][16];
    __shared__ float S[16][17];
    __shared__ float sh_logpi;
    const int k = blockIdx.x, t = threadIdx.x;

    const float4* src = (const float4*)(M + (size_t)k * 4096 + (size_t)t * 16);
    float4 a0 = src[0], a1 = src[1], a2 = src[2], a3 = src[3];
    ((float4*)Ml[t])[0] = a0; ((float4*)Ml[t])[1] = a1;
    ((float4*)Ml[t])[2] = a2; ((float4*)Ml[t])[3] = a3;

    if (t < 64) {
        float v = pi[t];
        float mx = v;
        for (int off = 32; off; off >>= 1) mx = fmaxf(mx, __shfl_xor(mx, off));
        float e = __expf(v - mx);
        float s = e;
        for (int off = 32; off; off >>= 1) s += __shfl_xor(s, off);
        if (t == 0) sh_logpi = pi[k] - mx - logf(s);
    }
    __syncthreads();

    {
        int r = t >> 4, c = t & 15;
        float s = (r == c) ? 1.0f : 0.0f;
        for (int p = 0; p < 256; ++p) s += Ml[p][r] * Ml[p][c];
        S[r][c] = s;
    }
    __syncthreads();

    for (int j = 0; j < 16; ++j) {
        if (t == 0) S[j][j] = sqrtf(S[j][j]);
        __syncthreads();
        if (t > j && t < 16) S[t][j] = S[t][j] / S[j][j];
        __syncthreads();
        {
            int r = t >> 4, c = t & 15;
            if (r > j && c > j && c <= r) S[r][c] -= S[r][j] * S[c][j];
        }
        __syncthreads();
    }

    if (t == 0) {
        float ldet = 0.0f;
        for (int j = 0; j < 16; ++j) ldet += logf(S[j][j]);
        cvec[k] = logSA - ldet + sh_logpi;
    }

    float m[16] = {a0.x, a0.y, a0.z, a0.w, a1.x, a1.y, a1.z, a1.w,
                   a2.x, a2.y, a2.z, a2.w, a3.x, a3.y, a3.z, a3.w};
    float y[16];
#pragma unroll
    for (int r = 0; r < 16; ++r) {
        float v = m[r];
#pragma unroll
        for (int q = 0; q < r; ++q) v -= S[r][q] * y[q];
        y[r] = v / S[r][r];
    }
    // fragment-native Bt write: cw=k>>2, n=k&3, lane=((t>>3)&3)*16+r, ks=t>>5, e=t&7
    const int cw = k >> 2, n = k & 3;
    const int ks = t >> 5, e = t & 7;
    const int lbase = ((t >> 3) & 3) * 16;
#pragma unroll
    for (int r = 0; r < 16; ++r) {
        const size_t off = (size_t)cw * 16384 + (size_t)ks * 2048 + (size_t)n * 512
                         + (size_t)(lbase + r) * 8 + e;
        Bt[off] = (__bf16)y[r];
    }
}

// ---------- kernel 2: X fp32 -> bf16 into fragment-native stripes ----------
// block b = stripe st (64 rows x 256 cols); LDS transpose staging.
__global__ __launch_bounds__(256) void convert_X(const float* __restrict__ X,
                                                 __bf16* __restrict__ Xb) {
    __shared__ __bf16 T[64][264];
    const int st = blockIdx.x;
    const int n0 = st * 64;
    const int t = threadIdx.x;

    // phase 1: coalesced f32 reads -> bf16 -> LDS
#pragma unroll
    for (int j = 0; j < 16; ++j) {
        const int u = j * 256 + t;
        const int r = u >> 6, c4 = u & 63;
        const int n = n0 + r;
        float4 v = make_float4(0.f, 0.f, 0.f, 0.f);
        if (n < NPTS) v = ((const float4*)X)[(size_t)n * 64 + c4];
        v4bf o = {(__bf16)v.x, (__bf16)v.y, (__bf16)v.z, (__bf16)v.w};
        *(v4bf*)&T[r][c4 * 4] = o;
    }
    __syncthreads();

    // phase 2: fragment-native coalesced writes (16B/lane)
#pragma unroll
    for (int ks = 0; ks < 8; ++ks) {
        const int mh = t >> 6;               // wave = 16-row group
        const int l = t & 63;
        const int row = mh * 16 + (l & 15);
        const int col = ks * 32 + (l >> 4) * 8;
        v8bf val = *(const v8bf*)&T[row][col];
        const size_t off = (size_t)st * 16384 + (size_t)ks * 2048
                         + (size_t)mh * 512 + (size_t)l * 8;
        *(v8bf*)(Xb + off) = val;
    }
}

// ---------- kernel 3: barrier-free LDS-free GEMM + fused density ----------
// Wave owns a 64-row stripe: X fragments (full K) live in 128 VGPRs; B fragments
// streamed from L2 per column-group. acc = mfma(bg, af) -> r-reduction lane-local.
__global__ __launch_bounds__(256, 2) void gemm_density(const __bf16* __restrict__ Xb,
                                                       const __bf16* __restrict__ Bt,
                                                       const float* __restrict__ cvec,
                                                       float* __restrict__ dens_t) {
    const int bid = blockIdx.x;
    const int xcd = bid & 7;
    const int w = threadIdx.x >> 6, lane = threadIdx.x & 63;
    const int widx = (bid >> 3) * 4 + w;     // 0..255 per XCD
    if (widx >= 196) return;                 // 196 stripes per XCD
    const int st = xcd * 196 + widx;
    const int laneoff = lane * 8;

    // load all A fragments for this stripe: 32 x dwordx4, 128 VGPR
    const __bf16* Ab = Xb + ((size_t)st << 14) + laneoff;
    v8bf af[8][4];
#pragma unroll
    for (int ks = 0; ks < 8; ++ks)
#pragma unroll
        for (int m = 0; m < 4; ++m)
            af[ks][m] = *(const v8bf*)(Ab + ks * 2048 + m * 512);

    const float4* cv4 = (const float4*)cvec;
    float* outbase = dens_t + ((size_t)st << 6) * 64;   // st*64 points * 64 comps

#pragma unroll 1
    for (int cw = 0; cw < 16; ++cw) {
        const __bf16* Bb = Bt + ((size_t)cw << 14) + laneoff;
        v4f acc[4][4] = {};
#pragma unroll
        for (int ks = 0; ks < 8; ++ks) {
            v8bf bg[4];
#pragma unroll
            for (int n = 0; n < 4; ++n) bg[n] = *(const v8bf*)(Bb + ks * 2048 + n * 512);
#pragma unroll
            for (int m = 0; m < 4; ++m)
#pragma unroll
                for (int n = 0; n < 4; ++n)
                    acc[m][n] = __builtin_amdgcn_mfma_f32_16x16x32_bf16(bg[n], af[ks][m], acc[m][n], 0, 0, 0);
        }

        const float4 cv = cv4[cw];
#pragma unroll
        for (int m = 0; m < 4; ++m) {
            v4f dq;
#pragma unroll
            for (int n = 0; n < 4; ++n) {
                v4f qv = acc[m][n];
                float s = qv[0] * qv[0] + qv[1] * qv[1] + qv[2] * qv[2] + qv[3] * qv[3];
                s += __shfl_xor(s, 16);
                s += __shfl_xor(s, 32);
                const float c = (n == 0) ? cv.x : (n == 1) ? cv.y : (n == 2) ? cv.z : cv.w;
                dq[n] = c - 128.0f * __logf(1.0f - s);
            }
            if (lane < 16) {
                // point = st*64 + m*16 + lane; write comps cw*4..cw*4+3
                *(v4f*)(outbase + ((size_t)(m * 16 + lane) << 6) + (cw << 2)) = dq;
            }
        }
    }
}

// ---------- kernel 4: logsumexp over 64 comps (contiguous per point), global sum ----------
__global__ __launch_bounds__(256) void reduce_ll(const float* __restrict__ dens_t,
                                                 float* __restrict__ out) {
    const int n = blockIdx.x * 256 + threadIdx.x;
    float local = 0.0f;
    if (n < NPTS) {
        const float4* p = (const float4*)(dens_t + ((size_t)n << 6));
        float4 d0 = p[0];
        float m = fmaxf(fmaxf(d0.x, d0.y), fmaxf(d0.z, d0.w));
        float s = __expf(d0.x - m) + __expf(d0.y - m) + __expf(d0.z - m) + __expf(d0.w - m);
#pragma unroll
        for (int j = 1; j < 16; ++j) {
            float4 d = p[j];
            float mt = fmaxf(fmaxf(d.x, d.y), fmaxf(d.z, d.w));
            float mn = fmaxf(m, mt);
            s = s * __expf(m - mn)
              + __expf(d.x - mn) + __expf(d.y - mn) + __expf(d.z - mn) + __expf(d.w - mn);
            m = mn;
        }
        local = m + __logf(s);
    }
    for (int off = 32; off; off >>= 1) local += __shfl_down(local, off);
    __shared__ float part[4];
    const int wv = threadIdx.x >> 6, lane = threadIdx.x & 63;
    if (lane == 0) part[wv] = local;
    __syncthreads();
    if (threadIdx.x == 0) atomicAdd(out, part[0] + part[1] + part[2] + part[3]);
}

extern "C" void kernel_launch(void* const* d_in, const int* in_sizes, int n_in,
                              void* d_out, int out_size, void* d_ws, size_t ws_size,
                              hipStream_t stream) {
    const float* X  = (const float*)d_in[0];
    const float* M  = (const float*)d_in[1];
    const float* pi = (const float*)d_in[2];
    float* out = (float*)d_out;

    char* ws = (char*)d_ws;
    __bf16* Xb     = (__bf16*)ws;                         // 1568*16384*2 = 51,380,224
    __bf16* Bt     = (__bf16*)(ws + 51380224);            // 16*16384*2   =    524,288
    float*  dens_t = (float*)(ws + 51904512);             // 100352*64*4  = 25,690,112
    float*  cvec   = (float*)(ws + 77594624);             // 256 B

    const double half_p = 128.0;
    const float logSA = (float)(lgamma(half_p) - log(2.0) - half_p * log(M_PI));

    hipMemsetAsync(d_out, 0, sizeof(float), stream);
    prep_comp<<<64, 256, 0, stream>>>(M, pi, Bt, cvec, logSA);
    convert_X<<<1568, 256, 0, stream>>>(X, Xb);
    gemm_density<<<512, 256, 0, stream>>>(Xb, Bt, cvec, dens_t);  // 2048 wave-slots, 1568 jobs
    reduce_ll<<<391, 256, 0, stream>>>(dens_t, out);
}